// Round 5
// baseline (222.197 us; speedup 1.0000x reference)
//
#include <hip/hip_runtime.h>
#include <math.h>

constexpr int B_  = 16;
constexpr int C_  = 1536;
constexpr int T_  = 2000;
constexpr int H_  = 128;
constexpr int C3_ = 3 * C_;   // 4608
constexpr int C2_ = 2 * C_;   // 3072
constexpr int NT_ = 8;        // t-parts for gemm2 (256 t each)

typedef short bf8 __attribute__((ext_vector_type(8)));   // 8 bf16 (4 VGPR) MFMA A/B frag
typedef short bf4 __attribute__((ext_vector_type(4)));   // 4 bf16 (8B)
typedef float f4  __attribute__((ext_vector_type(4)));   // MFMA C/D frag

// fp32 -> bf16 round-to-nearest-even (finite inputs only)
__device__ inline unsigned short f2b(float f) {
  unsigned int u = __builtin_bit_cast(unsigned int, f);
  unsigned int r = (u + 0x7FFFu + ((u >> 16) & 1u)) >> 16;
  return (unsigned short)r;
}

// ---------------- K1: masked per-(b,c) mean/std over T (one wave per row) ----
__global__ __launch_bounds__(256) void k_stats(
    const float* __restrict__ x, const float* __restrict__ mask,
    float* __restrict__ mean0, float* __restrict__ std0) {
  const int wave = threadIdx.x >> 6;
  const int lane = threadIdx.x & 63;
  const int row = blockIdx.x * 4 + wave;      // b*C + c
  const int b = row / C_;
  const float4* xr = (const float4*)(x + (size_t)row * T_);
  const float4* mr = (const float4*)(mask + (size_t)b * T_);
  float sm = 0.f, s1 = 0.f, s2 = 0.f;
  for (int i = lane; i < T_ / 4; i += 64) {
    float4 xv = xr[i];
    float4 mv = mr[i];
    sm += mv.x + mv.y + mv.z + mv.w;
    s1 += mv.x * xv.x + mv.y * xv.y + mv.z * xv.z + mv.w * xv.w;
    s2 += mv.x * xv.x * xv.x + mv.y * xv.y * xv.y + mv.z * xv.z * xv.z + mv.w * xv.w * xv.w;
  }
#pragma unroll
  for (int off = 32; off; off >>= 1) {
    sm += __shfl_xor(sm, off);
    s1 += __shfl_xor(s1, off);
    s2 += __shfl_xor(s2, off);
  }
  if (lane == 0) {
    float mean = s1 / sm;
    float var = s2 / sm - mean * mean;
    mean0[row] = mean;
    std0[row] = sqrtf(fmaxf(var, 1e-5f));
  }
}

// ---------------- K2: hconst[b,h] = b1 + w1[:,C:2C]@mean0 + w1[:,2C:3C]@std0 --
__global__ __launch_bounds__(256) void k_hconst(
    const float* __restrict__ w1, const float* __restrict__ b1,
    const float* __restrict__ mean0, const float* __restrict__ std0,
    float* __restrict__ hconst) {
  const int wave = threadIdx.x >> 6;
  const int lane = threadIdx.x & 63;
  const int idx = blockIdx.x * 4 + wave;      // b*H + h
  const int b = idx >> 7;
  const int h = idx & (H_ - 1);
  const float* wm  = w1 + (size_t)h * C3_ + C_;
  const float* wsd = wm + C_;
  const float* mn = mean0 + b * C_;
  const float* sd = std0 + b * C_;
  float s = 0.f;
  for (int c = lane; c < C_; c += 64)
    s += wm[c] * mn[c] + wsd[c] * sd[c];
#pragma unroll
  for (int off = 32; off; off >>= 1) s += __shfl_xor(s, off);
  if (lane == 0) hconst[idx] = s + b1[h];
}

// ---------------- K3: MFMA GEMM1 + relu + LN(H) + tanh -> hlnT[b][t][h] bf16 --
// block 256 thr (4 waves), tile 128h x 64t; wave w owns t-slice w*16..+15.
// LDS: A [128h][32k] bf16 rows 64B, B [64t][32k] bf16, XOR-swizzled, dbuf.
__global__ __launch_bounds__(256) void k_gemm1_ln(
    const float* __restrict__ x, const float* __restrict__ w1,
    const float* __restrict__ hconst, const float* __restrict__ g1,
    const float* __restrict__ be1, unsigned short* __restrict__ hlnT) {
  __shared__ __align__(16) short As[2][128 * 32];
  __shared__ __align__(16) short Bs[2][64 * 32];
  const int b = blockIdx.y;
  const int t0 = blockIdx.x * 64;
  const int tid = threadIdx.x;
  const int lane = tid & 63;
  const int w = tid >> 6;
  const int l15 = lane & 15;
  const int l4 = lane >> 4;

  float4 va[4], vb[2];

  f4 acc[8];
#pragma unroll
  for (int mi = 0; mi < 8; ++mi) { f4 z = {0.f, 0.f, 0.f, 0.f}; acc[mi] = z; }

  // ---- staging helpers (reg-staged: global fp32 -> regs -> bf16 LDS) ----
#define G1_GLOAD(K0)                                                          \
  {                                                                           \
    _Pragma("unroll")                                                         \
    for (int q = 0; q < 4; ++q) {                                             \
      int idx = q * 256 + tid;                                                \
      int row = idx >> 3, j4 = idx & 7;                                       \
      va[q] = *(const float4*)(w1 + (size_t)row * C3_ + (K0) + j4 * 4);       \
    }                                                                         \
    _Pragma("unroll")                                                         \
    for (int q = 0; q < 2; ++q) {                                             \
      int idx = q * 256 + tid;                                                \
      int k = idx >> 4, t4 = idx & 15;                                        \
      int t = t0 + t4 * 4;                                                    \
      if (t < T_)                                                             \
        vb[q] = *(const float4*)(x + ((size_t)(b * C_ + (K0) + k)) * T_ + t); \
      else                                                                    \
        vb[q] = make_float4(0.f, 0.f, 0.f, 0.f);                              \
    }                                                                         \
  }
#define G1_LSTORE(BUF)                                                        \
  {                                                                           \
    _Pragma("unroll")                                                         \
    for (int q = 0; q < 4; ++q) {                                             \
      int idx = q * 256 + tid;                                                \
      int row = idx >> 3, j4 = idx & 7;                                       \
      int slot = (j4 >> 1) ^ ((row >> 2) & 3);                                \
      bf4 p;                                                                  \
      p[0] = (short)f2b(va[q].x); p[1] = (short)f2b(va[q].y);                 \
      p[2] = (short)f2b(va[q].z); p[3] = (short)f2b(va[q].w);                 \
      *(bf4*)&As[BUF][row * 32 + slot * 8 + (j4 & 1) * 4] = p;                \
    }                                                                         \
    _Pragma("unroll")                                                         \
    for (int q = 0; q < 2; ++q) {                                             \
      int idx = q * 256 + tid;                                                \
      int k = idx >> 4, t4 = idx & 15;                                        \
      float vv[4] = {vb[q].x, vb[q].y, vb[q].z, vb[q].w};                     \
      _Pragma("unroll")                                                       \
      for (int j = 0; j < 4; ++j) {                                           \
        int row = t4 * 4 + j;                                                 \
        int slot = (k >> 3) ^ ((row >> 2) & 3);                               \
        Bs[BUF][row * 32 + slot * 8 + (k & 7)] = (short)f2b(vv[j]);           \
      }                                                                       \
    }                                                                         \
  }

  G1_GLOAD(0);
  G1_LSTORE(0);
  __syncthreads();

  const int fA = (l15 >> 2) & 3;        // row-swizzle term, mi/w-independent
  const int NS = C_ / 32;               // 48 K-steps
  for (int s = 0; s < NS; ++s) {
    const int cur = s & 1;
    if (s + 1 < NS) G1_GLOAD((s + 1) * 32);
    {
      const int browB = w * 16 + l15;
      bf8 bfr = *(const bf8*)&Bs[cur][browB * 32 + (l4 ^ fA) * 8];
#pragma unroll
      for (int mi = 0; mi < 8; ++mi) {
        bf8 afr = *(const bf8*)&As[cur][(mi * 16 + l15) * 32 + (l4 ^ fA) * 8];
        acc[mi] = __builtin_amdgcn_mfma_f32_16x16x32_bf16(afr, bfr, acc[mi], 0, 0, 0);
      }
    }
    if (s + 1 < NS) G1_LSTORE(cur ^ 1);
    __syncthreads();
  }

  // epilogue: +hconst, relu, LN over 128 h (per t-col), tanh, bf16 store
  const int t = t0 + w * 16 + l15;
  float sum = 0.f, ssq = 0.f;
#pragma unroll
  for (int mi = 0; mi < 8; ++mi) {
    float4 h4 = *(const float4*)(hconst + b * H_ + mi * 16 + l4 * 4);
    const float* hp = (const float*)&h4;
#pragma unroll
    for (int reg = 0; reg < 4; ++reg) {
      float v = fmaxf(acc[mi][reg] + hp[reg], 0.f);
      acc[mi][reg] = v;
      sum += v;
      ssq += v * v;
    }
  }
  sum += __shfl_xor(sum, 16); sum += __shfl_xor(sum, 32);
  ssq += __shfl_xor(ssq, 16); ssq += __shfl_xor(ssq, 32);
  const float mean = sum * (1.f / 128.f);
  const float rstd = rsqrtf(ssq * (1.f / 128.f) - mean * mean + 1e-5f);
  if (t < T_) {
    unsigned short* dst = hlnT + ((size_t)b * T_ + t) * H_;
#pragma unroll
    for (int mi = 0; mi < 8; ++mi) {
      float4 g4 = *(const float4*)(g1 + mi * 16 + l4 * 4);
      float4 e4 = *(const float4*)(be1 + mi * 16 + l4 * 4);
      const float* gp = (const float*)&g4;
      const float* ep = (const float*)&e4;
      bf4 p;
#pragma unroll
      for (int reg = 0; reg < 4; ++reg) {
        float o = tanhf((acc[mi][reg] - mean) * rstd * gp[reg] + ep[reg]);
        p[reg] = (short)f2b(o);
      }
      *(bf4*)&dst[mi * 16 + l4 * 4] = p;
    }
  }
}

// ---------------- K4: MFMA GEMM2 (alpha=w2@hln) + flash softmax + pooling ----
// grid (12 c-tiles, B, NT parts). Each part owns t in [part*256, min(+256,T)).
// Per-LANE online softmax state; lane-merge at end; per-part partials to ws;
// k_pool_merge LSE-merges the NT parts.
__global__ __launch_bounds__(256) void k_gemm2_pool(
    const float* __restrict__ x, const float* __restrict__ mask,
    const float* __restrict__ w2, const unsigned short* __restrict__ hlnT,
    float* __restrict__ pm, float* __restrict__ ps0,
    float* __restrict__ ps1, float* __restrict__ ps2) {
  __shared__ __align__(16) short Ws[128 * 128];     // [c][h] swizzled, 32KB
  __shared__ __align__(16) short Hs[2][64 * 128];   // [t][h] swizzled, 2x16KB
  const int b = blockIdx.y;
  const int c0 = blockIdx.x * 128;
  const int part = blockIdx.z;
  const int tb = part * (T_ / NT_ + (T_ % NT_ ? 1 : 0) > 256 ? 256 : 256);  // 256
  const int tb2 = part * 256;
  const int te = min(tb2 + 256, T_);
  const int tid = threadIdx.x;
  const int lane = tid & 63;
  const int w = tid >> 6;
  const int l15 = lane & 15;
  const int l4 = lane >> 4;
  (void)tb;

  // stage w2 tile (fp32, L2-resident) -> Ws bf16 once: 128 rows x 128 h
#pragma unroll
  for (int q = 0; q < 16; ++q) {
    int idx = q * 256 + tid;
    int row = idx >> 5, j4 = idx & 31;
    float4 v = *(const float4*)(w2 + (size_t)(c0 + row) * H_ + j4 * 4);
    bf4 p;
    p[0] = (short)f2b(v.x); p[1] = (short)f2b(v.y);
    p[2] = (short)f2b(v.z); p[3] = (short)f2b(v.w);
    int slot = (j4 >> 1) ^ (row & 15);
    *(bf4*)&Ws[row * 128 + slot * 8 + (j4 & 1) * 4] = p;
  }

  float mmax[8], s0[8], s1[8], s2[8];
#pragma unroll
  for (int r = 0; r < 8; ++r) { mmax[r] = -INFINITY; s0[r] = 0.f; s1[r] = 0.f; s2[r] = 0.f; }

  bf8 hreg[4];
#define G2_HLOAD(T0)                                                          \
  {                                                                           \
    _Pragma("unroll")                                                         \
    for (int q = 0; q < 4; ++q) {                                             \
      int idx = q * 256 + tid;                                                \
      int row = idx >> 4, slot = idx & 15;                                    \
      int t = (T0) + row;                                                     \
      if (t > T_ - 1) t = T_ - 1;                                             \
      hreg[q] = *(const bf8*)(hlnT + ((size_t)b * T_ + t) * H_ + slot * 8);   \
    }                                                                         \
  }
#define G2_HSTORE(BUF)                                                        \
  {                                                                           \
    _Pragma("unroll")                                                         \
    for (int q = 0; q < 4; ++q) {                                             \
      int idx = q * 256 + tid;                                                \
      int row = idx >> 4, slot = idx & 15;                                    \
      *(bf8*)&Hs[BUF][row * 128 + (slot ^ (row & 15)) * 8] = hreg[q];         \
    }                                                                         \
  }

  G2_HLOAD(tb2);
  G2_HSTORE(0);
  __syncthreads();

  const int NCH = (te - tb2 + 63) / 64;   // <= 4
  for (int ch = 0; ch < NCH; ++ch) {
    const int t0 = tb2 + ch * 64;
    const int cur = ch & 1;
    if (ch + 1 < NCH) G2_HLOAD(t0 + 64);

    // T14 issue-early: mask + x loads for this chunk, consumed after MFMA
    float mk[4];
    int tcol[4];
#pragma unroll
    for (int nj = 0; nj < 4; ++nj) {
      int t = t0 + nj * 16 + l15;
      tcol[nj] = (t < T_) ? t : (T_ - 1);
      mk[nj] = (t < T_) ? mask[(size_t)b * T_ + t] : 0.f;
    }
    float xv[8][4];
#pragma unroll
    for (int mi = 0; mi < 2; ++mi)
#pragma unroll
      for (int reg = 0; reg < 4; ++reg) {
        const int c = c0 + w * 32 + mi * 16 + l4 * 4 + reg;
        const float* xrow = x + ((size_t)(b * C_ + c)) * T_;
#pragma unroll
        for (int nj = 0; nj < 4; ++nj) xv[mi * 4 + reg][nj] = xrow[tcol[nj]];
      }

    f4 acc[2][4];
#pragma unroll
    for (int mi = 0; mi < 2; ++mi)
#pragma unroll
      for (int nj = 0; nj < 4; ++nj) { f4 z = {0.f, 0.f, 0.f, 0.f}; acc[mi][nj] = z; }

#pragma unroll
    for (int ks = 0; ks < 4; ++ks) {
      const int sw = (ks * 4 + l4) ^ l15;   // row&15 == l15 for both A rows
      bf8 a0 = *(const bf8*)&Ws[(w * 32 + l15) * 128 + sw * 8];
      bf8 a1 = *(const bf8*)&Ws[(w * 32 + 16 + l15) * 128 + sw * 8];
      bf8 bb[4];
#pragma unroll
      for (int nj = 0; nj < 4; ++nj)
        bb[nj] = *(const bf8*)&Hs[cur][(nj * 16 + l15) * 128 + sw * 8];
#pragma unroll
      for (int nj = 0; nj < 4; ++nj) {
        acc[0][nj] = __builtin_amdgcn_mfma_f32_16x16x32_bf16(a0, bb[nj], acc[0][nj], 0, 0, 0);
        acc[1][nj] = __builtin_amdgcn_mfma_f32_16x16x32_bf16(a1, bb[nj], acc[1][nj], 0, 0, 0);
      }
    }

    // HSTORE moved BEFORE the VALU-heavy epilogue: buffer cur^1 was drained at
    // the previous iteration's barrier, so this is safe and overlaps the
    // ds_write + vmcnt drain with the softmax tail.
    if (ch + 1 < NCH) G2_HSTORE(cur ^ 1);

    // epilogue: per-lane online softmax + pooled partial sums
#pragma unroll
    for (int mi = 0; mi < 2; ++mi)
#pragma unroll
      for (int reg = 0; reg < 4; ++reg) {
        const int r = mi * 4 + reg;
        float lm = mmax[r];
#pragma unroll
        for (int nj = 0; nj < 4; ++nj)
          if (mk[nj] != 0.f) lm = fmaxf(lm, acc[mi][nj][reg]);
        if (lm == -INFINITY) continue;
        const float scale = (mmax[r] == -INFINITY) ? 0.f : __expf(mmax[r] - lm);
        float a0 = s0[r] * scale, a1 = s1[r] * scale, a2 = s2[r] * scale;
#pragma unroll
        for (int nj = 0; nj < 4; ++nj) {
          if (mk[nj] != 0.f) {
            float e = __expf(acc[mi][nj][reg] - lm);
            float xvv = xv[r][nj];
            a0 += e; a1 += e * xvv; a2 += e * xvv * xvv;
          }
        }
        s0[r] = a0; s1[r] = a1; s2[r] = a2; mmax[r] = lm;
      }

    __syncthreads();
  }

  // merge the 16 lanes (cols) of each row group via log-sum-exp butterfly
#pragma unroll
  for (int off = 1; off < 16; off <<= 1) {
#pragma unroll
    for (int r = 0; r < 8; ++r) {
      float om = __shfl_xor(mmax[r], off);
      float o0 = __shfl_xor(s0[r], off);
      float o1 = __shfl_xor(s1[r], off);
      float o2 = __shfl_xor(s2[r], off);
      float mn = fmaxf(mmax[r], om);
      float e1 = (mmax[r] == -INFINITY) ? 0.f : __expf(mmax[r] - mn);
      float e2 = (om == -INFINITY) ? 0.f : __expf(om - mn);
      s0[r] = s0[r] * e1 + o0 * e2;
      s1[r] = s1[r] * e1 + o1 * e2;
      s2[r] = s2[r] * e1 + o2 * e2;
      mmax[r] = mn;
    }
  }
  if (l15 == 0) {
#pragma unroll
    for (int mi = 0; mi < 2; ++mi)
#pragma unroll
      for (int reg = 0; reg < 4; ++reg) {
        const int r = mi * 4 + reg;
        const int c = c0 + w * 32 + mi * 16 + l4 * 4 + reg;
        const size_t j = ((size_t)(b * NT_ + part)) * C_ + c;
        pm[j] = mmax[r]; ps0[j] = s0[r]; ps1[j] = s1[r]; ps2[j] = s2[r];
      }
  }
}

// ---------------- K4b: LSE-merge the NT t-part partials -> pooled ------------
__global__ __launch_bounds__(256) void k_pool_merge(
    const float* __restrict__ pm, const float* __restrict__ ps0,
    const float* __restrict__ ps1, const float* __restrict__ ps2,
    float* __restrict__ pooled) {
  const int idx = blockIdx.x * 256 + threadIdx.x;   // b*C + c
  const int b = idx / C_;
  const int c = idx - b * C_;
  float m = -INFINITY, s0 = 0.f, s1 = 0.f, s2 = 0.f;
#pragma unroll
  for (int p = 0; p < NT_; ++p) {
    const size_t j = ((size_t)(b * NT_ + p)) * C_ + c;
    float om = pm[j];
    if (om == -INFINITY) continue;
    float mn = fmaxf(m, om);
    float e1 = (m == -INFINITY) ? 0.f : __expf(m - mn);
    float e2 = __expf(om - mn);
    s0 = s0 * e1 + ps0[j] * e2;
    s1 = s1 * e1 + ps1[j] * e2;
    s2 = s2 * e1 + ps2[j] * e2;
    m = mn;
  }
  float mean = s1 / s0;
  float var = s2 / s0 - mean * mean;
  pooled[b * C2_ + c] = mean;
  pooled[b * C2_ + C_ + c] = sqrtf(fmaxf(var, 1e-5f));
}

// ---------------- K5: final LN over 2C channels per b -------------------------
__global__ __launch_bounds__(256) void k_final_ln(
    const float* __restrict__ pooled, const float* __restrict__ g2,
    const float* __restrict__ be2, float* __restrict__ out) {
  __shared__ float rs[8];
  const int b = blockIdx.x;
  const int tid = threadIdx.x;
  const int lane = tid & 63;
  const int wave = tid >> 6;
  const float* p = pooled + b * C2_;
  float s = 0.f, q = 0.f;
  for (int i = tid; i < C2_; i += 256) {
    float v = p[i];
    s += v;
    q += v * v;
  }
#pragma unroll
  for (int off = 32; off; off >>= 1) {
    s += __shfl_xor(s, off);
    q += __shfl_xor(q, off);
  }
  if (lane == 0) { rs[wave] = s; rs[4 + wave] = q; }
  __syncthreads();
  s = rs[0] + rs[1] + rs[2] + rs[3];
  q = rs[4] + rs[5] + rs[6] + rs[7];
  float mean = s * (1.f / C2_);
  float var = q * (1.f / C2_) - mean * mean;
  float rstd = rsqrtf(var + 1e-5f);
  for (int i = tid; i < C2_; i += 256)
    out[b * C2_ + i] = (p[i] - mean) * rstd * g2[i] + be2[i];
}

extern "C" void kernel_launch(void* const* d_in, const int* in_sizes, int n_in,
                              void* d_out, int out_size, void* d_ws, size_t ws_size,
                              hipStream_t stream) {
  const float* x    = (const float*)d_in[0];
  const float* mask = (const float*)d_in[1];
  const float* w1   = (const float*)d_in[2];
  const float* b1   = (const float*)d_in[3];
  const float* g1   = (const float*)d_in[4];
  const float* be1  = (const float*)d_in[5];
  const float* w2   = (const float*)d_in[6];
  // d_in[7] = b2: per-(b,c) constant on softmax logits -> softmax-invariant, dropped
  const float* g2   = (const float*)d_in[8];
  const float* be2  = (const float*)d_in[9];
  float* out = (float*)d_out;

  float* ws     = (float*)d_ws;
  float* mean0  = ws;                   // B*C
  float* std0   = mean0 + B_ * C_;      // B*C
  float* hconst = std0 + B_ * C_;       // B*H
  float* pooled = hconst + B_ * H_;     // B*2C
  float* pm     = pooled + B_ * C2_;    // B*NT*C each:
  float* ps0    = pm  + B_ * NT_ * C_;
  float* ps1    = ps0 + B_ * NT_ * C_;
  float* ps2    = ps1 + B_ * NT_ * C_;
  unsigned short* hlnT = (unsigned short*)(ps2 + B_ * NT_ * C_);  // B*T*H bf16, 8.2MB

  k_stats<<<dim3(B_ * C_ / 4), dim3(256), 0, stream>>>(x, mask, mean0, std0);
  k_hconst<<<dim3(B_ * H_ / 4), dim3(256), 0, stream>>>(w1, b1, mean0, std0, hconst);
  k_gemm1_ln<<<dim3((T_ + 63) / 64, B_), dim3(256), 0, stream>>>(x, w1, hconst, g1, be1, hlnT);
  k_gemm2_pool<<<dim3(C_ / 128, B_, NT_), dim3(256), 0, stream>>>(x, mask, w2, hlnT,
                                                                  pm, ps0, ps1, ps2);
  k_pool_merge<<<dim3(B_ * C_ / 256), dim3(256), 0, stream>>>(pm, ps0, ps1, ps2, pooled);
  k_final_ln<<<dim3(B_), dim3(256), 0, stream>>>(pooled, g2, be2, out);
}

// Round 6
// 165.025 us; speedup vs baseline: 1.3464x; 1.3464x over previous
//
#include <hip/hip_runtime.h>
#include <math.h>

constexpr int B_  = 16;
constexpr int C_  = 1536;
constexpr int T_  = 2000;
constexpr int H_  = 128;
constexpr int C3_ = 3 * C_;   // 4608
constexpr int C2_ = 2 * C_;   // 3072
constexpr int NT_ = 4;        // t-parts for gemm2 (512 t each)

typedef short bf8 __attribute__((ext_vector_type(8)));   // 8 bf16 (4 VGPR) MFMA A/B frag
typedef short bf4 __attribute__((ext_vector_type(4)));   // 4 bf16 (8B)
typedef float f4  __attribute__((ext_vector_type(4)));   // MFMA C/D frag

// fp32 -> bf16 round-to-nearest-even (finite inputs only)
__device__ inline unsigned short f2b(float f) {
  unsigned int u = __builtin_bit_cast(unsigned int, f);
  unsigned int r = (u + 0x7FFFu + ((u >> 16) & 1u)) >> 16;
  return (unsigned short)r;
}

// ---------------- K1: masked per-(b,c) mean/std over T (one wave per row) ----
__global__ __launch_bounds__(256) void k_stats(
    const float* __restrict__ x, const float* __restrict__ mask,
    float* __restrict__ mean0, float* __restrict__ std0) {
  const int wave = threadIdx.x >> 6;
  const int lane = threadIdx.x & 63;
  const int row = blockIdx.x * 4 + wave;      // b*C + c
  const int b = row / C_;
  const float4* xr = (const float4*)(x + (size_t)row * T_);
  const float4* mr = (const float4*)(mask + (size_t)b * T_);
  float sm = 0.f, s1 = 0.f, s2 = 0.f;
  for (int i = lane; i < T_ / 4; i += 64) {
    float4 xv = xr[i];
    float4 mv = mr[i];
    sm += mv.x + mv.y + mv.z + mv.w;
    s1 += mv.x * xv.x + mv.y * xv.y + mv.z * xv.z + mv.w * xv.w;
    s2 += mv.x * xv.x * xv.x + mv.y * xv.y * xv.y + mv.z * xv.z * xv.z + mv.w * xv.w * xv.w;
  }
#pragma unroll
  for (int off = 32; off; off >>= 1) {
    sm += __shfl_xor(sm, off);
    s1 += __shfl_xor(s1, off);
    s2 += __shfl_xor(s2, off);
  }
  if (lane == 0) {
    float mean = s1 / sm;
    float var = s2 / sm - mean * mean;
    mean0[row] = mean;
    std0[row] = sqrtf(fmaxf(var, 1e-5f));
  }
}

// ---------------- K2: hconst[b,h] = b1 + w1[:,C:2C]@mean0 + w1[:,2C:3C]@std0 --
__global__ __launch_bounds__(256) void k_hconst(
    const float* __restrict__ w1, const float* __restrict__ b1,
    const float* __restrict__ mean0, const float* __restrict__ std0,
    float* __restrict__ hconst) {
  const int wave = threadIdx.x >> 6;
  const int lane = threadIdx.x & 63;
  const int idx = blockIdx.x * 4 + wave;      // b*H + h
  const int b = idx >> 7;
  const int h = idx & (H_ - 1);
  const float* wm  = w1 + (size_t)h * C3_ + C_;
  const float* wsd = wm + C_;
  const float* mn = mean0 + b * C_;
  const float* sd = std0 + b * C_;
  float s = 0.f;
  for (int c = lane; c < C_; c += 64)
    s += wm[c] * mn[c] + wsd[c] * sd[c];
#pragma unroll
  for (int off = 32; off; off >>= 1) s += __shfl_xor(s, off);
  if (lane == 0) hconst[idx] = s + b1[h];
}

// ---------------- K2b: wl1[c] = sum_h |w2[c,h]|  (static logit upper bound) --
// Valid because |tanh| <= 1, so alpha[c,t] <= ||w2[c,:]||_1 exactly.
__global__ __launch_bounds__(256) void k_wl1(
    const float* __restrict__ w2, float* __restrict__ wl1) {
  const int wave = threadIdx.x >> 6;
  const int lane = threadIdx.x & 63;
  const int c = blockIdx.x * 4 + wave;
  const float* wr = w2 + (size_t)c * H_;
  float s = fabsf(wr[lane]) + fabsf(wr[lane + 64]);
#pragma unroll
  for (int off = 32; off; off >>= 1) s += __shfl_xor(s, off);
  if (lane == 0) wl1[c] = s;
}

// ---------------- K3: MFMA GEMM1 + relu + LN(H) + tanh -> hlnT[b][t][h] bf16 --
// block 256 thr (4 waves), tile 128h x 64t; wave w owns t-slice w*16..+15.
// LDS: A [128h][32k] bf16 rows 64B, B [64t][32k] bf16, XOR-swizzled, dbuf.
__global__ __launch_bounds__(256) void k_gemm1_ln(
    const float* __restrict__ x, const float* __restrict__ w1,
    const float* __restrict__ hconst, const float* __restrict__ g1,
    const float* __restrict__ be1, unsigned short* __restrict__ hlnT) {
  __shared__ __align__(16) short As[2][128 * 32];
  __shared__ __align__(16) short Bs[2][64 * 32];
  const int b = blockIdx.y;
  const int t0 = blockIdx.x * 64;
  const int tid = threadIdx.x;
  const int lane = tid & 63;
  const int w = tid >> 6;
  const int l15 = lane & 15;
  const int l4 = lane >> 4;

  float4 va[4], vb[2];

  f4 acc[8];
#pragma unroll
  for (int mi = 0; mi < 8; ++mi) { f4 z = {0.f, 0.f, 0.f, 0.f}; acc[mi] = z; }

  // ---- staging helpers (reg-staged: global fp32 -> regs -> bf16 LDS) ----
#define G1_GLOAD(K0)                                                          \
  {                                                                           \
    _Pragma("unroll")                                                         \
    for (int q = 0; q < 4; ++q) {                                             \
      int idx = q * 256 + tid;                                                \
      int row = idx >> 3, j4 = idx & 7;                                       \
      va[q] = *(const float4*)(w1 + (size_t)row * C3_ + (K0) + j4 * 4);       \
    }                                                                         \
    _Pragma("unroll")                                                         \
    for (int q = 0; q < 2; ++q) {                                             \
      int idx = q * 256 + tid;                                                \
      int k = idx >> 4, t4 = idx & 15;                                        \
      int t = t0 + t4 * 4;                                                    \
      if (t < T_)                                                             \
        vb[q] = *(const float4*)(x + ((size_t)(b * C_ + (K0) + k)) * T_ + t); \
      else                                                                    \
        vb[q] = make_float4(0.f, 0.f, 0.f, 0.f);                              \
    }                                                                         \
  }
#define G1_LSTORE(BUF)                                                        \
  {                                                                           \
    _Pragma("unroll")                                                         \
    for (int q = 0; q < 4; ++q) {                                             \
      int idx = q * 256 + tid;                                                \
      int row = idx >> 3, j4 = idx & 7;                                       \
      int slot = (j4 >> 1) ^ ((row >> 2) & 3);                                \
      bf4 p;                                                                  \
      p[0] = (short)f2b(va[q].x); p[1] = (short)f2b(va[q].y);                 \
      p[2] = (short)f2b(va[q].z); p[3] = (short)f2b(va[q].w);                 \
      *(bf4*)&As[BUF][row * 32 + slot * 8 + (j4 & 1) * 4] = p;                \
    }                                                                         \
    _Pragma("unroll")                                                         \
    for (int q = 0; q < 2; ++q) {                                             \
      int idx = q * 256 + tid;                                                \
      int k = idx >> 4, t4 = idx & 15;                                        \
      float vv[4] = {vb[q].x, vb[q].y, vb[q].z, vb[q].w};                     \
      _Pragma("unroll")                                                       \
      for (int j = 0; j < 4; ++j) {                                           \
        int row = t4 * 4 + j;                                                 \
        int slot = (k >> 3) ^ ((row >> 2) & 3);                               \
        Bs[BUF][row * 32 + slot * 8 + (k & 7)] = (short)f2b(vv[j]);           \
      }                                                                       \
    }                                                                         \
  }

  G1_GLOAD(0);
  G1_LSTORE(0);
  __syncthreads();

  const int fA = (l15 >> 2) & 3;        // row-swizzle term, mi/w-independent
  const int NS = C_ / 32;               // 48 K-steps
  for (int s = 0; s < NS; ++s) {
    const int cur = s & 1;
    if (s + 1 < NS) G1_GLOAD((s + 1) * 32);
    {
      const int browB = w * 16 + l15;
      bf8 bfr = *(const bf8*)&Bs[cur][browB * 32 + (l4 ^ fA) * 8];
#pragma unroll
      for (int mi = 0; mi < 8; ++mi) {
        bf8 afr = *(const bf8*)&As[cur][(mi * 16 + l15) * 32 + (l4 ^ fA) * 8];
        acc[mi] = __builtin_amdgcn_mfma_f32_16x16x32_bf16(afr, bfr, acc[mi], 0, 0, 0);
      }
    }
    if (s + 1 < NS) G1_LSTORE(cur ^ 1);
    __syncthreads();
  }

  // epilogue: +hconst, relu, LN over 128 h (per t-col), tanh, bf16 store
  const int t = t0 + w * 16 + l15;
  float sum = 0.f, ssq = 0.f;
#pragma unroll
  for (int mi = 0; mi < 8; ++mi) {
    float4 h4 = *(const float4*)(hconst + b * H_ + mi * 16 + l4 * 4);
    const float* hp = (const float*)&h4;
#pragma unroll
    for (int reg = 0; reg < 4; ++reg) {
      float v = fmaxf(acc[mi][reg] + hp[reg], 0.f);
      acc[mi][reg] = v;
      sum += v;
      ssq += v * v;
    }
  }
  sum += __shfl_xor(sum, 16); sum += __shfl_xor(sum, 32);
  ssq += __shfl_xor(ssq, 16); ssq += __shfl_xor(ssq, 32);
  const float mean = sum * (1.f / 128.f);
  const float rstd = rsqrtf(ssq * (1.f / 128.f) - mean * mean + 1e-5f);
  if (t < T_) {
    unsigned short* dst = hlnT + ((size_t)b * T_ + t) * H_;
#pragma unroll
    for (int mi = 0; mi < 8; ++mi) {
      float4 g4 = *(const float4*)(g1 + mi * 16 + l4 * 4);
      float4 e4 = *(const float4*)(be1 + mi * 16 + l4 * 4);
      const float* gp = (const float*)&g4;
      const float* ep = (const float*)&e4;
      bf4 p;
#pragma unroll
      for (int reg = 0; reg < 4; ++reg) {
        float o = tanhf((acc[mi][reg] - mean) * rstd * gp[reg] + ep[reg]);
        p[reg] = (short)f2b(o);
      }
      *(bf4*)&dst[mi * 16 + l4 * 4] = p;
    }
  }
}

// ---------------- K4: MFMA GEMM2 (alpha=w2@hln) + FIXED-MAX softmax + pooling -
// grid (12 c-tiles, B, NT parts). Each part owns t in [part*512, min(+512,T)).
// e = exp(alpha - wl1[c]) -- no running max, no rescale; Mc cancels in s1/s0.
// Per-lane partial sums; lane-merge (plain add); per-part partials to ws;
// k_pool_merge plain-sums the NT parts.
__global__ __launch_bounds__(256) void k_gemm2_pool(
    const float* __restrict__ x, const float* __restrict__ mask,
    const float* __restrict__ w2, const unsigned short* __restrict__ hlnT,
    const float* __restrict__ wl1,
    float* __restrict__ ps0, float* __restrict__ ps1, float* __restrict__ ps2) {
  __shared__ __align__(16) short Ws[128 * 128];     // [c][h] swizzled, 32KB
  __shared__ __align__(16) short Hs[2][64 * 128];   // [t][h] swizzled, 2x16KB
  const int b = blockIdx.y;
  const int c0 = blockIdx.x * 128;
  const int part = blockIdx.z;
  const int tb = part * 512;
  const int te = min(tb + 512, T_);
  const int tid = threadIdx.x;
  const int lane = tid & 63;
  const int w = tid >> 6;
  const int l15 = lane & 15;
  const int l4 = lane >> 4;

  // stage w2 tile (fp32, L2-resident) -> Ws bf16 once: 128 rows x 128 h
#pragma unroll
  for (int q = 0; q < 16; ++q) {
    int idx = q * 256 + tid;
    int row = idx >> 5, j4 = idx & 31;
    float4 v = *(const float4*)(w2 + (size_t)(c0 + row) * H_ + j4 * 4);
    bf4 p;
    p[0] = (short)f2b(v.x); p[1] = (short)f2b(v.y);
    p[2] = (short)f2b(v.z); p[3] = (short)f2b(v.w);
    int slot = (j4 >> 1) ^ (row & 15);
    *(bf4*)&Ws[row * 128 + slot * 8 + (j4 & 1) * 4] = p;
  }

  // static per-row logit bound Mc (exp arg <= ~0.05, never overflows)
  float Mc[8];
#pragma unroll
  for (int mi = 0; mi < 2; ++mi) {
    float4 m4 = *(const float4*)(wl1 + c0 + w * 32 + mi * 16 + l4 * 4);
    Mc[mi * 4 + 0] = m4.x; Mc[mi * 4 + 1] = m4.y;
    Mc[mi * 4 + 2] = m4.z; Mc[mi * 4 + 3] = m4.w;
  }

  float s0[8], s1[8], s2[8];
#pragma unroll
  for (int r = 0; r < 8; ++r) { s0[r] = 0.f; s1[r] = 0.f; s2[r] = 0.f; }

  bf8 hreg[4];
#define G2_HLOAD(T0)                                                          \
  {                                                                           \
    _Pragma("unroll")                                                         \
    for (int q = 0; q < 4; ++q) {                                             \
      int idx = q * 256 + tid;                                                \
      int row = idx >> 4, slot = idx & 15;                                    \
      int t = (T0) + row;                                                     \
      if (t > T_ - 1) t = T_ - 1;                                             \
      hreg[q] = *(const bf8*)(hlnT + ((size_t)b * T_ + t) * H_ + slot * 8);   \
    }                                                                         \
  }
#define G2_HSTORE(BUF)                                                        \
  {                                                                           \
    _Pragma("unroll")                                                         \
    for (int q = 0; q < 4; ++q) {                                             \
      int idx = q * 256 + tid;                                                \
      int row = idx >> 4, slot = idx & 15;                                    \
      *(bf8*)&Hs[BUF][row * 128 + (slot ^ (row & 15)) * 8] = hreg[q];         \
    }                                                                         \
  }

  G2_HLOAD(tb);
  G2_HSTORE(0);
  __syncthreads();

  const int NCH = (te - tb + 63) / 64;   // <= 8
  for (int ch = 0; ch < NCH; ++ch) {
    const int t0 = tb + ch * 64;
    const int cur = ch & 1;
    if (ch + 1 < NCH) G2_HLOAD(t0 + 64);

    // issue-early: mask + x loads for this chunk, consumed after MFMA
    float mk[4];
    int tcol[4];
#pragma unroll
    for (int nj = 0; nj < 4; ++nj) {
      int t = t0 + nj * 16 + l15;
      tcol[nj] = (t < T_) ? t : (T_ - 1);
      mk[nj] = (t < T_) ? mask[(size_t)b * T_ + t] : 0.f;
    }
    float xv[8][4];
#pragma unroll
    for (int mi = 0; mi < 2; ++mi)
#pragma unroll
      for (int reg = 0; reg < 4; ++reg) {
        const int c = c0 + w * 32 + mi * 16 + l4 * 4 + reg;
        const float* xrow = x + ((size_t)(b * C_ + c)) * T_;
#pragma unroll
        for (int nj = 0; nj < 4; ++nj) xv[mi * 4 + reg][nj] = xrow[tcol[nj]];
      }

    f4 acc[2][4];
#pragma unroll
    for (int mi = 0; mi < 2; ++mi)
#pragma unroll
      for (int nj = 0; nj < 4; ++nj) { f4 z = {0.f, 0.f, 0.f, 0.f}; acc[mi][nj] = z; }

#pragma unroll
    for (int ks = 0; ks < 4; ++ks) {
      const int sw = (ks * 4 + l4) ^ l15;   // row&15 == l15 for both A rows
      bf8 a0 = *(const bf8*)&Ws[(w * 32 + l15) * 128 + sw * 8];
      bf8 a1 = *(const bf8*)&Ws[(w * 32 + 16 + l15) * 128 + sw * 8];
      bf8 bb[4];
#pragma unroll
      for (int nj = 0; nj < 4; ++nj)
        bb[nj] = *(const bf8*)&Hs[cur][(nj * 16 + l15) * 128 + sw * 8];
#pragma unroll
      for (int nj = 0; nj < 4; ++nj) {
        acc[0][nj] = __builtin_amdgcn_mfma_f32_16x16x32_bf16(a0, bb[nj], acc[0][nj], 0, 0, 0);
        acc[1][nj] = __builtin_amdgcn_mfma_f32_16x16x32_bf16(a1, bb[nj], acc[1][nj], 0, 0, 0);
      }
    }

    // epilogue: fixed-max exp + pooled partial sums (no serial chain)
#pragma unroll
    for (int mi = 0; mi < 2; ++mi)
#pragma unroll
      for (int reg = 0; reg < 4; ++reg) {
        const int r = mi * 4 + reg;
        float a0 = s0[r], a1 = s1[r], a2 = s2[r];
#pragma unroll
        for (int nj = 0; nj < 4; ++nj) {
          float e = (mk[nj] != 0.f) ? __expf(acc[mi][nj][reg] - Mc[r]) : 0.f;
          float xvv = xv[r][nj];
          a0 += e; a1 += e * xvv; a2 += e * xvv * xvv;
        }
        s0[r] = a0; s1[r] = a1; s2[r] = a2;
      }

    // HSTORE after the epilogue: the epilogue VALU hides this iter's HLOAD
    // latency; buffer cur^1 was drained at the previous iteration's barrier.
    if (ch + 1 < NCH) G2_HSTORE(cur ^ 1);
    __syncthreads();
  }

  // merge the 16 lanes (t-cols) of each row group: plain adds
#pragma unroll
  for (int off = 1; off < 16; off <<= 1) {
#pragma unroll
    for (int r = 0; r < 8; ++r) {
      s0[r] += __shfl_xor(s0[r], off);
      s1[r] += __shfl_xor(s1[r], off);
      s2[r] += __shfl_xor(s2[r], off);
    }
  }
  if (l15 == 0) {
#pragma unroll
    for (int mi = 0; mi < 2; ++mi)
#pragma unroll
      for (int reg = 0; reg < 4; ++reg) {
        const int r = mi * 4 + reg;
        const int c = c0 + w * 32 + mi * 16 + l4 * 4 + reg;
        const size_t j = ((size_t)(b * NT_ + part)) * C_ + c;
        ps0[j] = s0[r]; ps1[j] = s1[r]; ps2[j] = s2[r];
      }
  }
}

// ---------------- K4b: plain-sum the NT t-part partials -> pooled ------------
__global__ __launch_bounds__(256) void k_pool_merge(
    const float* __restrict__ ps0, const float* __restrict__ ps1,
    const float* __restrict__ ps2, float* __restrict__ pooled) {
  const int idx = blockIdx.x * 256 + threadIdx.x;   // b*C + c
  const int b = idx / C_;
  const int c = idx - b * C_;
  float s0 = 0.f, s1 = 0.f, s2 = 0.f;
#pragma unroll
  for (int p = 0; p < NT_; ++p) {
    const size_t j = ((size_t)(b * NT_ + p)) * C_ + c;
    s0 += ps0[j]; s1 += ps1[j]; s2 += ps2[j];
  }
  float mean = s1 / s0;
  float var = s2 / s0 - mean * mean;
  pooled[b * C2_ + c] = mean;
  pooled[b * C2_ + C_ + c] = sqrtf(fmaxf(var, 1e-5f));
}

// ---------------- K5: final LN over 2C channels per b -------------------------
__global__ __launch_bounds__(256) void k_final_ln(
    const float* __restrict__ pooled, const float* __restrict__ g2,
    const float* __restrict__ be2, float* __restrict__ out) {
  __shared__ float rs[8];
  const int b = blockIdx.x;
  const int tid = threadIdx.x;
  const int lane = tid & 63;
  const int wave = tid >> 6;
  const float* p = pooled + b * C2_;
  float s = 0.f, q = 0.f;
  for (int i = tid; i < C2_; i += 256) {
    float v = p[i];
    s += v;
    q += v * v;
  }
#pragma unroll
  for (int off = 32; off; off >>= 1) {
    s += __shfl_xor(s, off);
    q += __shfl_xor(q, off);
  }
  if (lane == 0) { rs[wave] = s; rs[4 + wave] = q; }
  __syncthreads();
  s = rs[0] + rs[1] + rs[2] + rs[3];
  q = rs[4] + rs[5] + rs[6] + rs[7];
  float mean = s * (1.f / C2_);
  float var = q * (1.f / C2_) - mean * mean;
  float rstd = rsqrtf(var + 1e-5f);
  for (int i = tid; i < C2_; i += 256)
    out[b * C2_ + i] = (p[i] - mean) * rstd * g2[i] + be2[i];
}

extern "C" void kernel_launch(void* const* d_in, const int* in_sizes, int n_in,
                              void* d_out, int out_size, void* d_ws, size_t ws_size,
                              hipStream_t stream) {
  const float* x    = (const float*)d_in[0];
  const float* mask = (const float*)d_in[1];
  const float* w1   = (const float*)d_in[2];
  const float* b1   = (const float*)d_in[3];
  const float* g1   = (const float*)d_in[4];
  const float* be1  = (const float*)d_in[5];
  const float* w2   = (const float*)d_in[6];
  // d_in[7] = b2: per-(b,c) constant on softmax logits -> softmax-invariant, dropped
  const float* g2   = (const float*)d_in[8];
  const float* be2  = (const float*)d_in[9];
  float* out = (float*)d_out;

  float* ws     = (float*)d_ws;
  float* mean0  = ws;                   // B*C
  float* std0   = mean0 + B_ * C_;      // B*C
  float* hconst = std0 + B_ * C_;       // B*H
  float* pooled = hconst + B_ * H_;     // B*2C
  float* wl1    = pooled + B_ * C2_;    // C
  float* ps0    = wl1 + C_;             // B*NT*C each:
  float* ps1    = ps0 + B_ * NT_ * C_;
  float* ps2    = ps1 + B_ * NT_ * C_;
  unsigned short* hlnT = (unsigned short*)(ps2 + B_ * NT_ * C_);  // B*T*H bf16, 8.2MB

  k_stats<<<dim3(B_ * C_ / 4), dim3(256), 0, stream>>>(x, mask, mean0, std0);
  k_hconst<<<dim3(B_ * H_ / 4), dim3(256), 0, stream>>>(w1, b1, mean0, std0, hconst);
  k_wl1<<<dim3(C_ / 4), dim3(256), 0, stream>>>(w2, wl1);
  k_gemm1_ln<<<dim3((T_ + 63) / 64, B_), dim3(256), 0, stream>>>(x, w1, hconst, g1, be1, hlnT);
  k_gemm2_pool<<<dim3(C_ / 128, B_, NT_), dim3(256), 0, stream>>>(x, mask, w2, hlnT, wl1,
                                                                  ps0, ps1, ps2);
  k_pool_merge<<<dim3(B_ * C_ / 256), dim3(256), 0, stream>>>(ps0, ps1, ps2, pooled);
  k_final_ln<<<dim3(B_), dim3(256), 0, stream>>>(pooled, g2, be2, out);
}